// Round 5
// baseline (119.820 us; speedup 1.0000x reference)
//
#include <hip/hip_runtime.h>

#define PH 7
#define PW 7
#define SP 4
#define C 10
#define FH 34
#define FW 34
#define NBIN (PH*PW)       // 49
#define PLANE (FH*FW)      // 1156
#define NP (NBIN*PLANE)    // 56644 floats per channel
#define RPB 512            // rois per block
#define NOUTC (C*NBIN)     // 490
#define TJ 32              // rois per transpose tile
#define PADW 37            // padded tile row (odd -> bank stride 5, coprime 32)

// ---- per-(roi, p) separable axis weights -------------------------------
// tabH[p*N+n] = {rw0, rw1, rw2, float(Y0*8+cnty)}  (h axis, p as ph)
// tabW[p*N+n] = {cw0, cw1, cw2, float(X0*8+cntx)}  (w axis, p as pw)
__global__ __launch_bounds__(256) void precompute(const float* __restrict__ rois,
                                                  float4* __restrict__ tabH,
                                                  float4* __restrict__ tabW, int N) {
#pragma clang fp contract(off)
    int t = blockIdx.x * 256 + threadIdx.x;
    if (t >= 7 * N) return;
    int n = t / 7;
    int p = t - n * 7;
    const float* r = rois + n * 5;
    float rsw = r[1] * 0.125f;
    float rsh = r[2] * 0.125f;
    float rew = r[3] * 0.125f;
    float reh = r[4] * 0.125f;
    float dh = reh - rsh; float roi_h = (dh > 0.1f) ? dh : 0.1f;
    float dw = rew - rsw; float roi_w = (dw > 0.1f) ? dw : 0.1f;
    float bin_h = roi_h / 7.0f;
    float bin_w = roi_w / 7.0f;
    float sub_h = bin_h / 4.0f;
    float sub_w = bin_w / 4.0f;
    float hstart = floorf(rsh + (float)p * bin_h);
    float wstart = floorf(rsw + (float)p * bin_w);
    int Y0 = (int)hstart;
    int X0 = (int)wstart;

    float rw0 = 0.f, rw1 = 0.f, rw2 = 0.f; int cnty = 0;
#pragma unroll
    for (int s = 0; s < SP; ++s) {
        float hh = hstart + ((float)s + 0.5f) * sub_h;
        if (hh > -1.0f && hh < (float)FH) {
            ++cnty;
            float y1f = floorf(hh);
            float dy  = hh - y1f;
            int   y1  = (int)y1f;
            int   y2  = (int)ceilf(hh);
            float w1  = (1.0f - dy) * ((y1 >= 0 && y1 < FH) ? 1.0f : 0.0f);
            float w2  = dy          * ((y2 >= 0 && y2 < FH) ? 1.0f : 0.0f);
            int o1 = y1 - Y0;
            int o2 = y2 - Y0;
            rw0 += (o1 == 0) ? w1 : 0.0f;
            rw1 += (o1 == 1) ? w1 : 0.0f;
            rw1 += (o2 == 1) ? w2 : 0.0f;
            rw2 += (o2 == 2) ? w2 : 0.0f;
        }
    }
    float cw0 = 0.f, cw1 = 0.f, cw2 = 0.f; int cntx = 0;
#pragma unroll
    for (int s = 0; s < SP; ++s) {
        float ww = wstart + ((float)s + 0.5f) * sub_w;
        if (ww > -1.0f && ww < (float)FW) {
            ++cntx;
            float x1f = floorf(ww);
            float dx  = ww - x1f;
            int   x1  = (int)x1f;
            int   x2  = (int)ceilf(ww);
            float w1  = (1.0f - dx) * ((x1 >= 0 && x1 < FW) ? 1.0f : 0.0f);
            float w2  = dx          * ((x2 >= 0 && x2 < FW) ? 1.0f : 0.0f);
            int o1 = x1 - X0;
            int o2 = x2 - X0;
            cw0 += (o1 == 0) ? w1 : 0.0f;
            cw1 += (o1 == 1) ? w1 : 0.0f;
            cw1 += (o2 == 1) ? w2 : 0.0f;
            cw2 += (o2 == 2) ? w2 : 0.0f;
        }
    }
    tabH[p * N + n] = make_float4(rw0, rw1, rw2, (float)(Y0 * 8 + cnty));
    tabW[p * N + n] = make_float4(cw0, cw1, cw2, (float)(X0 * 8 + cntx));
}

// ---- main: block = (bin, 512-roi chunk); split slab in LDS; 3x3 window -
// LDS 46.2 KB -> 3 blocks/CU = 24 waves/CU. launch_bounds(512,6) caps VGPR at 85.
__global__ __launch_bounds__(RPB, 6) void roi_kernel(const float* __restrict__ ft,
                                                     const float4* __restrict__ tabH,
                                                     const float4* __restrict__ tabW,
                                                     float* __restrict__ ws2,
                                                     int N, int blocksPerBin) {
#pragma clang fp contract(off)
    __shared__ float4 ldsA[PLANE * 2];         // channels 0-7: [pix*2+q], 36992 B
    __shared__ float2 ldsB[PLANE];             // channels 8-9: [pix],      9248 B

    const int bin   = blockIdx.x / blocksPerBin;
    const int chunk = blockIdx.x % blocksPerBin;
    const int tid   = threadIdx.x;
    const int ph    = bin / PW;
    const int pw    = bin % PW;

    // stage: consecutive-float4-per-lane LDS writes (conflict-free b128)
    {
        const float* base = ft + (size_t)bin * PLANE;
        for (int idx = tid; idx < 2 * PLANE; idx += RPB) {
            int yx = idx >> 1;
            int q  = idx & 1;
            const float* b0 = base + (size_t)(q * 4) * NP + yx;
            float4 v;
            v.x = b0[0];
            v.y = b0[NP];
            v.z = b0[2 * NP];
            v.w = b0[3 * NP];
            ldsA[idx] = v;
        }
        const float* b8 = base + (size_t)8 * NP;
        for (int yx = tid; yx < PLANE; yx += RPB) {
            float2 v;
            v.x = b8[yx];
            v.y = b8[NP + yx];
            ldsB[yx] = v;
        }
    }
    __syncthreads();

    const int n = chunk * RPB + tid;
    if (n >= N) return;

    float4 th = tabH[ph * N + n];              // coalesced: lane stride 16B
    float4 tw = tabW[pw * N + n];
    int hp = (int)th.w; int Y0 = hp >> 3; int cnty = hp & 7;
    int wp = (int)tw.w; int X0 = wp >> 3; int cntx = wp & 7;
    float rw[3] = {th.x, th.y, th.z};
    float cw[3] = {tw.x, tw.y, tw.z};

    float4 a0 = make_float4(0.f,0.f,0.f,0.f);
    float4 a1 = make_float4(0.f,0.f,0.f,0.f);
    float  a8 = 0.f, a9 = 0.f;
#pragma unroll
    for (int j = 0; j < 3; ++j) {
        int y = min(max(Y0 + j, 0), FH - 1);
        float wy = rw[j];
#pragma unroll
        for (int i = 0; i < 3; ++i) {
            int x = min(max(X0 + i, 0), FW - 1);
            float w = wy * cw[i];
            int pix = y * FW + x;
            float4 f0 = ldsA[pix * 2];
            float4 f1 = ldsA[pix * 2 + 1];
            float2 f2 = ldsB[pix];
            a0.x += w * f0.x; a0.y += w * f0.y; a0.z += w * f0.z; a0.w += w * f0.w;
            a1.x += w * f1.x; a1.y += w * f1.y; a1.z += w * f1.z; a1.w += w * f1.w;
            a8   += w * f2.x; a9   += w * f2.y;
        }
    }

    int cnt = cntx * cnty;
    float inv = (cnt > 0) ? 1.0f / (float)cnt : 0.0f;

    // ws2[(bin*C + c) * N + n] : lane-stride 4B, fully coalesced
    float* o = ws2 + (size_t)(bin * C) * N + n;
    o[0 * (size_t)N] = a0.x * inv;
    o[1 * (size_t)N] = a0.y * inv;
    o[2 * (size_t)N] = a0.z * inv;
    o[3 * (size_t)N] = a0.w * inv;
    o[4 * (size_t)N] = a1.x * inv;
    o[5 * (size_t)N] = a1.y * inv;
    o[6 * (size_t)N] = a1.z * inv;
    o[7 * (size_t)N] = a1.w * inv;
    o[8 * (size_t)N] = a8   * inv;
    o[9 * (size_t)N] = a9   * inv;
}

// ---- ws2 (490 x N, row r = bin*10+c) -> out (N x 490, col = c*49+bin) --
__global__ __launch_bounds__(512) void transpose_out(const float* __restrict__ ws2,
                                                     float* __restrict__ out, int N) {
    __shared__ float t[NOUTC * PADW];          // 72520 B
    int n0  = blockIdx.x * TJ;
    int tid = threadIdx.x;
    bool fast = (n0 + TJ <= N) && ((N & 3) == 0);

    if (fast) {
        const float4* ws4 = (const float4*)ws2;
        int N4  = N >> 2;
        int n04 = n0 >> 2;
        for (int idx = tid; idx < NOUTC * (TJ / 4); idx += 512) {
            int r = idx >> 3;                  // TJ/4 == 8
            int k = idx & 7;
            float4 v = ws4[(size_t)r * N4 + n04 + k];
            float* dst = &t[r * PADW + 4 * k];
            dst[0] = v.x; dst[1] = v.y; dst[2] = v.z; dst[3] = v.w;
        }
    } else {
        for (int idx = tid; idx < NOUTC * TJ; idx += 512) {
            int r = idx / TJ;
            int j = idx - r * TJ;
            int n = n0 + j;
            t[r * PADW + j] = (n < N) ? ws2[(size_t)r * N + n] : 0.0f;
        }
    }
    __syncthreads();

    if (fast) {
        float2* out2 = (float2*)out;
        for (int idx = tid; idx < TJ * (NOUTC / 2); idx += 512) {
            int j  = idx / (NOUTC / 2);
            int t2 = idx - j * (NOUTC / 2);
            int col0 = 2 * t2, col1 = col0 + 1;
            int c0 = col0 / NBIN, b0 = col0 - c0 * NBIN;
            int c1 = col1 / NBIN, b1 = col1 - c1 * NBIN;
            float2 v;
            v.x = t[(b0 * C + c0) * PADW + j];
            v.y = t[(b1 * C + c1) * PADW + j];
            out2[(size_t)(n0 + j) * (NOUTC / 2) + t2] = v;
        }
    } else {
        for (int idx = tid; idx < TJ * NOUTC; idx += 512) {
            int j   = idx / NOUTC;
            int col = idx - j * NOUTC;
            int c   = col / NBIN;
            int b   = col - c * NBIN;
            int n   = n0 + j;
            if (n < N) out[(size_t)n * NOUTC + col] = t[(b * C + c) * PADW + j];
        }
    }
}

// ---- fallback (ws too small): inline math, direct strided store --------
__global__ __launch_bounds__(256) void roi_direct(const float* __restrict__ ft,
                                                  const float* __restrict__ rois,
                                                  float* __restrict__ out, int N) {
#pragma clang fp contract(off)
    int tid = blockIdx.x * blockDim.x + threadIdx.x;
    if (tid >= N * NBIN) return;
    int bin = tid % NBIN;
    int n   = tid / NBIN;
    int ph  = bin / PW;
    int pw  = bin % PW;
    const float* r = rois + n * 5;
    float rsw = r[1]*0.125f, rsh = r[2]*0.125f, rew = r[3]*0.125f, reh = r[4]*0.125f;
    float dh = reh - rsh; float roi_h = (dh > 0.1f) ? dh : 0.1f;
    float dw = rew - rsw; float roi_w = (dw > 0.1f) ? dw : 0.1f;
    float bin_h = roi_h / 7.0f, bin_w = roi_w / 7.0f;
    float sub_h = bin_h / 4.0f, sub_w = bin_w / 4.0f;
    float hstart = floorf(rsh + (float)ph * bin_h);
    float wstart = floorf(rsw + (float)pw * bin_w);
    int Y0 = (int)hstart, X0 = (int)wstart;
    float rw[3] = {0.f,0.f,0.f}, cw[3] = {0.f,0.f,0.f};
    int cnty = 0, cntx = 0;
    for (int s = 0; s < SP; ++s) {
        float hh = hstart + ((float)s + 0.5f) * sub_h;
        if (hh > -1.0f && hh < (float)FH) {
            ++cnty;
            float y1f = floorf(hh); float dy = hh - y1f;
            int y1 = (int)y1f, y2 = (int)ceilf(hh);
            float w1 = (1.0f-dy) * ((y1>=0&&y1<FH)?1.f:0.f);
            float w2 = dy        * ((y2>=0&&y2<FH)?1.f:0.f);
            if (y1-Y0>=0 && y1-Y0<3) rw[y1-Y0] += w1;
            if (y2-Y0>=0 && y2-Y0<3) rw[y2-Y0] += w2;
        }
        float ww = wstart + ((float)s + 0.5f) * sub_w;
        if (ww > -1.0f && ww < (float)FW) {
            ++cntx;
            float x1f = floorf(ww); float dx = ww - x1f;
            int x1 = (int)x1f, x2 = (int)ceilf(ww);
            float w1 = (1.0f-dx) * ((x1>=0&&x1<FW)?1.f:0.f);
            float w2 = dx        * ((x2>=0&&x2<FW)?1.f:0.f);
            if (x1-X0>=0 && x1-X0<3) cw[x1-X0] += w1;
            if (x2-X0>=0 && x2-X0<3) cw[x2-X0] += w2;
        }
    }
    float acc[C];
    for (int c = 0; c < C; ++c) acc[c] = 0.0f;
    const float* base = ft + (size_t)bin * PLANE;
    for (int j = 0; j < 3; ++j) {
        int y = min(max(Y0 + j, 0), FH - 1);
        for (int i = 0; i < 3; ++i) {
            int x = min(max(X0 + i, 0), FW - 1);
            float w = rw[j] * cw[i];
            int off = y * FW + x;
            for (int c = 0; c < C; ++c)
                acc[c] += w * base[(size_t)c * NP + off];
        }
    }
    int cnt = cntx * cnty;
    float inv = (cnt > 0) ? 1.0f / (float)cnt : 0.0f;
    float* o = out + (size_t)n * NOUTC + bin;
    for (int c = 0; c < C; ++c) o[c * NBIN] = acc[c] * inv;
}

extern "C" void kernel_launch(void* const* d_in, const int* in_sizes, int n_in,
                              void* d_out, int out_size, void* d_ws, size_t ws_size,
                              hipStream_t stream) {
    const float* ft   = (const float*)d_in[0];
    const float* rois = (const float*)d_in[1];
    float* out = (float*)d_out;
    int N = in_sizes[1] / 5;

    size_t ws2Bytes  = ((size_t)NOUTC * N * sizeof(float) + 255) & ~(size_t)255;
    size_t tabBytes  = (size_t)7 * N * sizeof(float4);
    size_t need      = ws2Bytes + 2 * tabBytes;

    if (ws_size >= need) {
        float*  ws2  = (float*)d_ws;
        float4* tabH = (float4*)((char*)d_ws + ws2Bytes);
        float4* tabW = tabH + (size_t)7 * N;

        int pblocks = (7 * N + 255) / 256;
        precompute<<<pblocks, 256, 0, stream>>>(rois, tabH, tabW, N);

        int blocksPerBin = (N + RPB - 1) / RPB;
        roi_kernel<<<NBIN * blocksPerBin, RPB, 0, stream>>>(ft, tabH, tabW, ws2,
                                                            N, blocksPerBin);

        int tblocks = (N + TJ - 1) / TJ;
        transpose_out<<<tblocks, 512, 0, stream>>>(ws2, out, N);
    } else {
        int total = N * NBIN;
        roi_direct<<<(total + 255) / 256, 256, 0, stream>>>(ft, rois, out, N);
    }
}

// Round 7
// 97.475 us; speedup vs baseline: 1.2292x; 1.2292x over previous
//
#include <hip/hip_runtime.h>

#define PH 7
#define PW 7
#define SP 4
#define C 10
#define FH 34
#define FW 34
#define NBIN (PH*PW)       // 49
#define PLANE (FH*FW)      // 1156
#define NP (NBIN*PLANE)    // 56644 floats per channel
#define RPB 512            // rois per block
#define NOUTC (C*NBIN)     // 490
#define TJ 32              // rois per transpose tile
#define PADW 37            // padded tile row (odd -> coprime with 32 banks)

// ---- per-(roi, p) separable axis weights -------------------------------
// Weights are pre-scaled by 1/count (0 if count==0) and pre-shifted so the
// stored base index is already clamped to [0, F-3]: taps outside [0,F-1]
// provably have zero weight, so the shift is lossless.
// Shift identity: row (Y0c + k) corresponds to original tap m = k - dY,
// dY = Y0 - Y0c  =>  h_k = W_{k-dY}  (selector out of {0,1,2} -> 0).
// tabH[p*N+n] = {h0, h1, h2, float(Y0c)}
// tabW[p*N+n] = {g0, g1, g2, float(X0c)}
__global__ __launch_bounds__(256) void precompute(const float* __restrict__ rois,
                                                  float4* __restrict__ tabH,
                                                  float4* __restrict__ tabW, int N) {
#pragma clang fp contract(off)
    int t = blockIdx.x * 256 + threadIdx.x;
    if (t >= 7 * N) return;
    int n = t / 7;
    int p = t - n * 7;
    const float* r = rois + n * 5;
    float rsw = r[1] * 0.125f;
    float rsh = r[2] * 0.125f;
    float rew = r[3] * 0.125f;
    float reh = r[4] * 0.125f;
    float dh = reh - rsh; float roi_h = (dh > 0.1f) ? dh : 0.1f;
    float dw = rew - rsw; float roi_w = (dw > 0.1f) ? dw : 0.1f;
    float bin_h = roi_h / 7.0f;
    float bin_w = roi_w / 7.0f;
    float sub_h = bin_h / 4.0f;
    float sub_w = bin_w / 4.0f;
    float hstart = floorf(rsh + (float)p * bin_h);
    float wstart = floorf(rsw + (float)p * bin_w);
    int Y0 = (int)floorf(hstart);
    int X0 = (int)floorf(wstart);

    float rw0 = 0.f, rw1 = 0.f, rw2 = 0.f; int cnty = 0;
#pragma unroll
    for (int s = 0; s < SP; ++s) {
        float hh = hstart + ((float)s + 0.5f) * sub_h;
        if (hh > -1.0f && hh < (float)FH) {
            ++cnty;
            float y1f = floorf(hh);
            float dy  = hh - y1f;
            int   y1  = (int)y1f;
            int   y2  = (int)ceilf(hh);
            float w1  = (1.0f - dy) * ((y1 >= 0 && y1 < FH) ? 1.0f : 0.0f);
            float w2  = dy          * ((y2 >= 0 && y2 < FH) ? 1.0f : 0.0f);
            int o1 = y1 - Y0;
            int o2 = y2 - Y0;
            rw0 += (o1 == 0) ? w1 : 0.0f;
            rw1 += (o1 == 1) ? w1 : 0.0f;
            rw1 += (o2 == 1) ? w2 : 0.0f;
            rw2 += (o2 == 2) ? w2 : 0.0f;
        }
    }
    float cw0 = 0.f, cw1 = 0.f, cw2 = 0.f; int cntx = 0;
#pragma unroll
    for (int s = 0; s < SP; ++s) {
        float ww = wstart + ((float)s + 0.5f) * sub_w;
        if (ww > -1.0f && ww < (float)FW) {
            ++cntx;
            float x1f = floorf(ww);
            float dx  = ww - x1f;
            int   x1  = (int)x1f;
            int   x2  = (int)ceilf(ww);
            float w1  = (1.0f - dx) * ((x1 >= 0 && x1 < FW) ? 1.0f : 0.0f);
            float w2  = dx          * ((x2 >= 0 && x2 < FW) ? 1.0f : 0.0f);
            int o1 = x1 - X0;
            int o2 = x2 - X0;
            cw0 += (o1 == 0) ? w1 : 0.0f;
            cw1 += (o1 == 1) ? w1 : 0.0f;
            cw1 += (o2 == 1) ? w2 : 0.0f;
            cw2 += (o2 == 2) ? w2 : 0.0f;
        }
    }

    // scale by 1/count (0 if no valid samples -> whole output row is 0)
    float ry = (cnty > 0) ? 1.0f / (float)cnty : 0.0f;
    float cx = (cntx > 0) ? 1.0f / (float)cntx : 0.0f;
    float W0 = rw0 * ry, W1 = rw1 * ry, W2 = rw2 * ry;
    float V0 = cw0 * cx, V1 = cw1 * cx, V2 = cw2 * cx;

    // shift so base is in [0, F-3]
    int Y0c = min(max(Y0, 0), FH - 3);
    int dY  = Y0 - Y0c;
    int X0c = min(max(X0, 0), FW - 3);
    int dX  = X0 - X0c;

    // h_k = W_{k-dY}; selector outside {0,1,2} -> 0 (those taps have 0 weight)
    int m0 = 0 - dY, m1 = 1 - dY, m2 = 2 - dY;
    float h0 = (m0 == 0) ? W0 : (m0 == 1) ? W1 : (m0 == 2) ? W2 : 0.0f;
    float h1 = (m1 == 0) ? W0 : (m1 == 1) ? W1 : (m1 == 2) ? W2 : 0.0f;
    float h2 = (m2 == 0) ? W0 : (m2 == 1) ? W1 : (m2 == 2) ? W2 : 0.0f;
    int k0 = 0 - dX, k1 = 1 - dX, k2 = 2 - dX;
    float g0 = (k0 == 0) ? V0 : (k0 == 1) ? V1 : (k0 == 2) ? V2 : 0.0f;
    float g1 = (k1 == 0) ? V0 : (k1 == 1) ? V1 : (k1 == 2) ? V2 : 0.0f;
    float g2 = (k2 == 0) ? V0 : (k2 == 1) ? V1 : (k2 == 2) ? V2 : 0.0f;

    tabH[p * N + n] = make_float4(h0, h1, h2, (float)Y0c);
    tabW[p * N + n] = make_float4(g0, g1, g2, (float)X0c);
}

// ---- main: block = (bin, 512-roi chunk); split slab in LDS; 3x3 window -
// LDS 46.2 KB + launch_bounds(512,6) -> 3 blocks/CU = 24 waves/CU.
// Body is deliberately minimal (no clamps / counts / divides) to fit the
// 85-VGPR budget without spilling.
__global__ __launch_bounds__(RPB, 6) void roi_kernel(const float* __restrict__ ft,
                                                     const float4* __restrict__ tabH,
                                                     const float4* __restrict__ tabW,
                                                     float* __restrict__ ws2,
                                                     int N, int blocksPerBin) {
    __shared__ float4 ldsA[PLANE * 2];         // channels 0-7: [pix*2+q], 36992 B
    __shared__ float2 ldsB[PLANE];             // channels 8-9: [pix],      9248 B

    const int bin   = blockIdx.x / blocksPerBin;
    const int chunk = blockIdx.x % blocksPerBin;
    const int tid   = threadIdx.x;
    const int ph    = bin / PW;
    const int pw    = bin % PW;

    // stage: consecutive-float4-per-lane LDS writes (conflict-free b128)
    {
        const float* base = ft + (size_t)bin * PLANE;
        for (int idx = tid; idx < 2 * PLANE; idx += RPB) {
            int yx = idx >> 1;
            int q  = idx & 1;
            const float* b0 = base + (size_t)(q * 4) * NP + yx;
            float4 v;
            v.x = b0[0];
            v.y = b0[NP];
            v.z = b0[2 * NP];
            v.w = b0[3 * NP];
            ldsA[idx] = v;
        }
        const float* b8 = base + (size_t)8 * NP;
        for (int yx = tid; yx < PLANE; yx += RPB) {
            float2 v;
            v.x = b8[yx];
            v.y = b8[NP + yx];
            ldsB[yx] = v;
        }
    }
    __syncthreads();

    const int n = chunk * RPB + tid;
    if (n >= N) return;

    float4 th = tabH[ph * N + n];              // coalesced: lane stride 16B
    float4 tw = tabW[pw * N + n];
    const int base = (int)th.w * FW + (int)tw.w;
    float rw[3] = {th.x, th.y, th.z};
    float cw[3] = {tw.x, tw.y, tw.z};

    float4 a0 = make_float4(0.f,0.f,0.f,0.f);
    float4 a1 = make_float4(0.f,0.f,0.f,0.f);
    float  a8 = 0.f, a9 = 0.f;
#pragma unroll
    for (int j = 0; j < 3; ++j) {
        float wy = rw[j];
#pragma unroll
        for (int i = 0; i < 3; ++i) {
            float w = wy * cw[i];
            int pix = base + j * FW + i;
            float4 f0 = ldsA[pix * 2];
            float4 f1 = ldsA[pix * 2 + 1];
            float2 f2 = ldsB[pix];
            a0.x += w * f0.x; a0.y += w * f0.y; a0.z += w * f0.z; a0.w += w * f0.w;
            a1.x += w * f1.x; a1.y += w * f1.y; a1.z += w * f1.z; a1.w += w * f1.w;
            a8   += w * f2.x; a9   += w * f2.y;
        }
    }

    // ws2[(bin*C + c) * N + n] : lane-stride 4B, fully coalesced
    float* o = ws2 + (size_t)(bin * C) * N + n;
    o[0 * (size_t)N] = a0.x;
    o[1 * (size_t)N] = a0.y;
    o[2 * (size_t)N] = a0.z;
    o[3 * (size_t)N] = a0.w;
    o[4 * (size_t)N] = a1.x;
    o[5 * (size_t)N] = a1.y;
    o[6 * (size_t)N] = a1.z;
    o[7 * (size_t)N] = a1.w;
    o[8 * (size_t)N] = a8;
    o[9 * (size_t)N] = a9;
}

// ---- ws2 (490 x N, row r = bin*10+c) -> out (N x 490, col = c*49+bin) --
__global__ __launch_bounds__(512) void transpose_out(const float* __restrict__ ws2,
                                                     float* __restrict__ out, int N) {
    __shared__ float t[NOUTC * PADW];          // 72520 B
    int n0  = blockIdx.x * TJ;
    int tid = threadIdx.x;
    bool fast = (n0 + TJ <= N) && ((N & 3) == 0);

    if (fast) {
        const float4* ws4 = (const float4*)ws2;
        int N4  = N >> 2;
        int n04 = n0 >> 2;
        for (int idx = tid; idx < NOUTC * (TJ / 4); idx += 512) {
            int r = idx >> 3;                  // TJ/4 == 8
            int k = idx & 7;
            float4 v = ws4[(size_t)r * N4 + n04 + k];
            float* dst = &t[r * PADW + 4 * k];
            dst[0] = v.x; dst[1] = v.y; dst[2] = v.z; dst[3] = v.w;
        }
    } else {
        for (int idx = tid; idx < NOUTC * TJ; idx += 512) {
            int r = idx / TJ;
            int j = idx - r * TJ;
            int n = n0 + j;
            t[r * PADW + j] = (n < N) ? ws2[(size_t)r * N + n] : 0.0f;
        }
    }
    __syncthreads();

    if (fast) {
        float2* out2 = (float2*)out;
        for (int idx = tid; idx < TJ * (NOUTC / 2); idx += 512) {
            int j  = idx / (NOUTC / 2);
            int t2 = idx - j * (NOUTC / 2);
            int col0 = 2 * t2, col1 = col0 + 1;
            int c0 = col0 / NBIN, b0 = col0 - c0 * NBIN;
            int c1 = col1 / NBIN, b1 = col1 - c1 * NBIN;
            float2 v;
            v.x = t[(b0 * C + c0) * PADW + j];
            v.y = t[(b1 * C + c1) * PADW + j];
            out2[(size_t)(n0 + j) * (NOUTC / 2) + t2] = v;
        }
    } else {
        for (int idx = tid; idx < TJ * NOUTC; idx += 512) {
            int j   = idx / NOUTC;
            int col = idx - j * NOUTC;
            int c   = col / NBIN;
            int b   = col - c * NBIN;
            int n   = n0 + j;
            if (n < N) out[(size_t)n * NOUTC + col] = t[(b * C + c) * PADW + j];
        }
    }
}

// ---- fallback (ws too small): inline math, direct strided store --------
__global__ __launch_bounds__(256) void roi_direct(const float* __restrict__ ft,
                                                  const float* __restrict__ rois,
                                                  float* __restrict__ out, int N) {
#pragma clang fp contract(off)
    int tid = blockIdx.x * blockDim.x + threadIdx.x;
    if (tid >= N * NBIN) return;
    int bin = tid % NBIN;
    int n   = tid / NBIN;
    int ph  = bin / PW;
    int pw  = bin % PW;
    const float* r = rois + n * 5;
    float rsw = r[1]*0.125f, rsh = r[2]*0.125f, rew = r[3]*0.125f, reh = r[4]*0.125f;
    float dh = reh - rsh; float roi_h = (dh > 0.1f) ? dh : 0.1f;
    float dw = rew - rsw; float roi_w = (dw > 0.1f) ? dw : 0.1f;
    float bin_h = roi_h / 7.0f, bin_w = roi_w / 7.0f;
    float sub_h = bin_h / 4.0f, sub_w = bin_w / 4.0f;
    float hstart = floorf(rsh + (float)ph * bin_h);
    float wstart = floorf(rsw + (float)pw * bin_w);
    int Y0 = (int)hstart, X0 = (int)wstart;
    float rw[3] = {0.f,0.f,0.f}, cw[3] = {0.f,0.f,0.f};
    int cnty = 0, cntx = 0;
    for (int s = 0; s < SP; ++s) {
        float hh = hstart + ((float)s + 0.5f) * sub_h;
        if (hh > -1.0f && hh < (float)FH) {
            ++cnty;
            float y1f = floorf(hh); float dy = hh - y1f;
            int y1 = (int)y1f, y2 = (int)ceilf(hh);
            float w1 = (1.0f-dy) * ((y1>=0&&y1<FH)?1.f:0.f);
            float w2 = dy        * ((y2>=0&&y2<FH)?1.f:0.f);
            if (y1-Y0>=0 && y1-Y0<3) rw[y1-Y0] += w1;
            if (y2-Y0>=0 && y2-Y0<3) rw[y2-Y0] += w2;
        }
        float ww = wstart + ((float)s + 0.5f) * sub_w;
        if (ww > -1.0f && ww < (float)FW) {
            ++cntx;
            float x1f = floorf(ww); float dx = ww - x1f;
            int x1 = (int)x1f, x2 = (int)ceilf(ww);
            float w1 = (1.0f-dx) * ((x1>=0&&x1<FW)?1.f:0.f);
            float w2 = dx        * ((x2>=0&&x2<FW)?1.f:0.f);
            if (x1-X0>=0 && x1-X0<3) cw[x1-X0] += w1;
            if (x2-X0>=0 && x2-X0<3) cw[x2-X0] += w2;
        }
    }
    float acc[C];
    for (int c = 0; c < C; ++c) acc[c] = 0.0f;
    const float* base = ft + (size_t)bin * PLANE;
    for (int j = 0; j < 3; ++j) {
        int y = min(max(Y0 + j, 0), FH - 1);
        for (int i = 0; i < 3; ++i) {
            int x = min(max(X0 + i, 0), FW - 1);
            float w = rw[j] * cw[i];
            int off = y * FW + x;
            for (int c = 0; c < C; ++c)
                acc[c] += w * base[(size_t)c * NP + off];
        }
    }
    int cnt = cntx * cnty;
    float inv = (cnt > 0) ? 1.0f / (float)cnt : 0.0f;
    float* o = out + (size_t)n * NOUTC + bin;
    for (int c = 0; c < C; ++c) o[c * NBIN] = acc[c] * inv;
}

extern "C" void kernel_launch(void* const* d_in, const int* in_sizes, int n_in,
                              void* d_out, int out_size, void* d_ws, size_t ws_size,
                              hipStream_t stream) {
    const float* ft   = (const float*)d_in[0];
    const float* rois = (const float*)d_in[1];
    float* out = (float*)d_out;
    int N = in_sizes[1] / 5;

    size_t ws2Bytes  = ((size_t)NOUTC * N * sizeof(float) + 255) & ~(size_t)255;
    size_t tabBytes  = (size_t)7 * N * sizeof(float4);
    size_t need      = ws2Bytes + 2 * tabBytes;

    if (ws_size >= need) {
        float*  ws2  = (float*)d_ws;
        float4* tabH = (float4*)((char*)d_ws + ws2Bytes);
        float4* tabW = tabH + (size_t)7 * N;

        int pblocks = (7 * N + 255) / 256;
        precompute<<<pblocks, 256, 0, stream>>>(rois, tabH, tabW, N);

        int blocksPerBin = (N + RPB - 1) / RPB;
        roi_kernel<<<NBIN * blocksPerBin, RPB, 0, stream>>>(ft, tabH, tabW, ws2,
                                                            N, blocksPerBin);

        int tblocks = (N + TJ - 1) / TJ;
        transpose_out<<<tblocks, 512, 0, stream>>>(ws2, out, N);
    } else {
        int total = N * NBIN;
        roi_direct<<<(total + 255) / 256, 256, 0, stream>>>(ft, rois, out, N);
    }
}

// Round 8
// 90.576 us; speedup vs baseline: 1.3229x; 1.0762x over previous
//
#include <hip/hip_runtime.h>

#define PH 7
#define PW 7
#define SP 4
#define C 10
#define FH 34
#define FW 34
#define NBIN (PH*PW)       // 49
#define PLANE (FH*FW)      // 1156
#define NP (NBIN*PLANE)    // 56644 floats per channel
#define RPB 512            // rois per block
#define NOUTC (C*NBIN)     // 490
#define TJ 16              // rois per transpose tile
#define PADW 17            // padded tile row (odd -> coprime with 32 banks)

// Per-axis separable weights over the 3-wide window, pre-scaled by 1/count
// (0 if count==0) and pre-shifted so base is clamped to [0, F-3].
// Shift identity (verified R7): h_k = w_{k-dB}, dB = B0 - B0clamped.
struct AxisW { float w0, w1, w2; int base; };

__device__ __forceinline__ AxisW axis_weights(float rs, float re, int p, int F) {
#pragma clang fp contract(off)
    float d  = re - rs;
    float sp = (d > 0.1f) ? d : 0.1f;
    float bs = sp / 7.0f;
    float ss = bs / 4.0f;
    float st = floorf(rs + (float)p * bs);
    int   B0 = (int)floorf(st);

    float w0 = 0.f, w1 = 0.f, w2 = 0.f; int cnt = 0;
#pragma unroll
    for (int s = 0; s < SP; ++s) {
        float v = st + ((float)s + 0.5f) * ss;
        if (v > -1.0f && v < (float)F) {
            ++cnt;
            float f1 = floorf(v);
            float dv = v - f1;
            int   i1 = (int)f1;
            int   i2 = (int)ceilf(v);
            float a  = (1.0f - dv) * ((i1 >= 0 && i1 < F) ? 1.0f : 0.0f);
            float b  = dv          * ((i2 >= 0 && i2 < F) ? 1.0f : 0.0f);
            int o1 = i1 - B0;
            int o2 = i2 - B0;
            w0 += (o1 == 0) ? a : 0.0f;
            w1 += (o1 == 1) ? a : 0.0f;
            w1 += (o2 == 1) ? b : 0.0f;
            w2 += (o2 == 2) ? b : 0.0f;
        }
    }
    float rc = (cnt > 0) ? 1.0f / (float)cnt : 0.0f;
    w0 *= rc; w1 *= rc; w2 *= rc;

    int Bc = min(max(B0, 0), F - 3);
    int dB = B0 - Bc;
    int m0 = 0 - dB, m1 = 1 - dB, m2 = 2 - dB;
    AxisW out;
    out.w0 = (m0 == 0) ? w0 : (m0 == 1) ? w1 : (m0 == 2) ? w2 : 0.0f;
    out.w1 = (m1 == 0) ? w0 : (m1 == 1) ? w1 : (m1 == 2) ? w2 : 0.0f;
    out.w2 = (m2 == 0) ? w0 : (m2 == 1) ? w1 : (m2 == 2) ? w2 : 0.0f;
    out.base = Bc;
    return out;
}

// ---- main: block = (bin, 512-roi chunk); split slab in LDS; 3x3 window -
// LDS 46.2 KB + launch_bounds(512,6) -> 3 blocks/CU = 24 waves/CU.
// Axis weights computed inline (before the barrier, hiding under staging
// latency) -- no precompute kernel, no tables.
__global__ __launch_bounds__(RPB, 6) void roi_kernel(const float* __restrict__ ft,
                                                     const float* __restrict__ rois,
                                                     float* __restrict__ ws2,
                                                     int N, int blocksPerBin) {
    __shared__ float4 ldsA[PLANE * 2];         // channels 0-7: [pix*2+q], 36992 B
    __shared__ float2 ldsB[PLANE];             // channels 8-9: [pix],      9248 B

    const int bin   = blockIdx.x / blocksPerBin;
    const int chunk = blockIdx.x % blocksPerBin;
    const int tid   = threadIdx.x;
    const int ph    = bin / PW;
    const int pw    = bin % PW;

    // stage: consecutive-float4-per-lane LDS writes (conflict-free b128)
    {
        const float* base = ft + (size_t)bin * PLANE;
        for (int idx = tid; idx < 2 * PLANE; idx += RPB) {
            int yx = idx >> 1;
            int q  = idx & 1;
            const float* b0 = base + (size_t)(q * 4) * NP + yx;
            float4 v;
            v.x = b0[0];
            v.y = b0[NP];
            v.z = b0[2 * NP];
            v.w = b0[3 * NP];
            ldsA[idx] = v;
        }
        const float* b8 = base + (size_t)8 * NP;
        for (int yx = tid; yx < PLANE; yx += RPB) {
            float2 v;
            v.x = b8[yx];
            v.y = b8[NP + yx];
            ldsB[yx] = v;
        }
    }

    // per-roi coordinate math: independent of LDS, overlaps staging latency
    const int n = chunk * RPB + tid;
    const int nv = (n < N) ? n : 0;            // clamp for safe load; masked later
    const float* r = rois + nv * 5;
    float rx1 = r[1] * 0.125f;
    float ry1 = r[2] * 0.125f;
    float rx2 = r[3] * 0.125f;
    float ry2 = r[4] * 0.125f;
    AxisW H = axis_weights(ry1, ry2, ph, FH);
    AxisW W = axis_weights(rx1, rx2, pw, FW);
    const int base = H.base * FW + W.base;
    float rw[3] = {H.w0, H.w1, H.w2};
    float cw[3] = {W.w0, W.w1, W.w2};

    __syncthreads();

    if (n >= N) return;

    float4 a0 = make_float4(0.f,0.f,0.f,0.f);
    float4 a1 = make_float4(0.f,0.f,0.f,0.f);
    float  a8 = 0.f, a9 = 0.f;
#pragma unroll
    for (int j = 0; j < 3; ++j) {
        float wy = rw[j];
#pragma unroll
        for (int i = 0; i < 3; ++i) {
            float w = wy * cw[i];
            int pix = base + j * FW + i;
            float4 f0 = ldsA[pix * 2];
            float4 f1 = ldsA[pix * 2 + 1];
            float2 f2 = ldsB[pix];
            a0.x += w * f0.x; a0.y += w * f0.y; a0.z += w * f0.z; a0.w += w * f0.w;
            a1.x += w * f1.x; a1.y += w * f1.y; a1.z += w * f1.z; a1.w += w * f1.w;
            a8   += w * f2.x; a9   += w * f2.y;
        }
    }

    // ws2[(bin*C + c) * N + n] : lane-stride 4B, fully coalesced
    float* o = ws2 + (size_t)(bin * C) * N + n;
    o[0 * (size_t)N] = a0.x;
    o[1 * (size_t)N] = a0.y;
    o[2 * (size_t)N] = a0.z;
    o[3 * (size_t)N] = a0.w;
    o[4 * (size_t)N] = a1.x;
    o[5 * (size_t)N] = a1.y;
    o[6 * (size_t)N] = a1.z;
    o[7 * (size_t)N] = a1.w;
    o[8 * (size_t)N] = a8;
    o[9 * (size_t)N] = a9;
}

// ---- ws2 (490 x N, row r = bin*10+c) -> out (N x 490, col = c*49+bin) --
// TJ=16, 256 threads: 625 blocks, 33.3 KB LDS -> 4 blocks/CU, good balance.
__global__ __launch_bounds__(256) void transpose_out(const float* __restrict__ ws2,
                                                     float* __restrict__ out, int N) {
    __shared__ float t[NOUTC * PADW];          // 33320 B
    int n0  = blockIdx.x * TJ;
    int tid = threadIdx.x;
    bool fast = (n0 + TJ <= N) && ((N & 3) == 0);

    if (fast) {
        const float4* ws4 = (const float4*)ws2;
        int N4  = N >> 2;
        int n04 = n0 >> 2;
        for (int idx = tid; idx < NOUTC * (TJ / 4); idx += 256) {
            int r = idx >> 2;                  // TJ/4 == 4
            int k = idx & 3;
            float4 v = ws4[(size_t)r * N4 + n04 + k];
            float* dst = &t[r * PADW + 4 * k];
            dst[0] = v.x; dst[1] = v.y; dst[2] = v.z; dst[3] = v.w;
        }
    } else {
        for (int idx = tid; idx < NOUTC * TJ; idx += 256) {
            int r = idx / TJ;
            int j = idx - r * TJ;
            int n = n0 + j;
            t[r * PADW + j] = (n < N) ? ws2[(size_t)r * N + n] : 0.0f;
        }
    }
    __syncthreads();

    if (fast) {
        float2* out2 = (float2*)out;
        for (int idx = tid; idx < TJ * (NOUTC / 2); idx += 256) {
            int j  = idx / (NOUTC / 2);
            int t2 = idx - j * (NOUTC / 2);
            int col0 = 2 * t2, col1 = col0 + 1;
            int c0 = col0 / NBIN, b0 = col0 - c0 * NBIN;
            int c1 = col1 / NBIN, b1 = col1 - c1 * NBIN;
            float2 v;
            v.x = t[(b0 * C + c0) * PADW + j];
            v.y = t[(b1 * C + c1) * PADW + j];
            out2[(size_t)(n0 + j) * (NOUTC / 2) + t2] = v;
        }
    } else {
        for (int idx = tid; idx < TJ * NOUTC; idx += 256) {
            int j   = idx / NOUTC;
            int col = idx - j * NOUTC;
            int c   = col / NBIN;
            int b   = col - c * NBIN;
            int n   = n0 + j;
            if (n < N) out[(size_t)n * NOUTC + col] = t[(b * C + c) * PADW + j];
        }
    }
}

// ---- fallback (ws too small): inline math, direct strided store --------
__global__ __launch_bounds__(256) void roi_direct(const float* __restrict__ ft,
                                                  const float* __restrict__ rois,
                                                  float* __restrict__ out, int N) {
#pragma clang fp contract(off)
    int tid = blockIdx.x * blockDim.x + threadIdx.x;
    if (tid >= N * NBIN) return;
    int bin = tid % NBIN;
    int n   = tid / NBIN;
    int ph  = bin / PW;
    int pw  = bin % PW;
    const float* r = rois + n * 5;
    float rsw = r[1]*0.125f, rsh = r[2]*0.125f, rew = r[3]*0.125f, reh = r[4]*0.125f;
    AxisW H = axis_weights(rsh, reh, ph, FH);
    AxisW W = axis_weights(rsw, rew, pw, FW);
    float rw[3] = {H.w0, H.w1, H.w2};
    float cw[3] = {W.w0, W.w1, W.w2};
    float acc[C];
    for (int c = 0; c < C; ++c) acc[c] = 0.0f;
    const float* base = ft + (size_t)bin * PLANE;
    for (int j = 0; j < 3; ++j) {
        int y = H.base + j;
        for (int i = 0; i < 3; ++i) {
            int x = W.base + i;
            float w = rw[j] * cw[i];
            int off = y * FW + x;
            for (int c = 0; c < C; ++c)
                acc[c] += w * base[(size_t)c * NP + off];
        }
    }
    float* o = out + (size_t)n * NOUTC + bin;
    for (int c = 0; c < C; ++c) o[c * NBIN] = acc[c];
}

extern "C" void kernel_launch(void* const* d_in, const int* in_sizes, int n_in,
                              void* d_out, int out_size, void* d_ws, size_t ws_size,
                              hipStream_t stream) {
    const float* ft   = (const float*)d_in[0];
    const float* rois = (const float*)d_in[1];
    float* out = (float*)d_out;
    int N = in_sizes[1] / 5;

    size_t need = (size_t)NOUTC * N * sizeof(float);

    if (ws_size >= need) {
        float* ws2 = (float*)d_ws;
        int blocksPerBin = (N + RPB - 1) / RPB;
        roi_kernel<<<NBIN * blocksPerBin, RPB, 0, stream>>>(ft, rois, ws2,
                                                            N, blocksPerBin);
        int tblocks = (N + TJ - 1) / TJ;
        transpose_out<<<tblocks, 256, 0, stream>>>(ws2, out, N);
    } else {
        int total = N * NBIN;
        roi_direct<<<(total + 255) / 256, 256, 0, stream>>>(ft, rois, out, N);
    }
}

// Round 9
// 86.490 us; speedup vs baseline: 1.3854x; 1.0472x over previous
//
#include <hip/hip_runtime.h>

#define PH 7
#define PW 7
#define SP 4
#define C 10
#define FH 34
#define FW 34
#define NBIN (PH*PW)       // 49
#define PLANE (FH*FW)      // 1156
#define NP (NBIN*PLANE)    // 56644 floats per channel
#define RPB 1024           // rois per block -> 490 blocks, all co-resident
#define NOUTC (C*NBIN)     // 490
#define TJ 16              // rois per transpose tile
#define PADW 17            // padded tile row (odd -> coprime with 32 banks)

// bf16 helpers (bit-ops; inputs finite)
__device__ __forceinline__ unsigned short f2bf_rne(float v) {
    unsigned int u = __float_as_uint(v);
    u += 0x7FFFu + ((u >> 16) & 1u);       // round-to-nearest-even
    return (unsigned short)(u >> 16);
}
__device__ __forceinline__ float bf2f(unsigned short h) {
    return __uint_as_float((unsigned int)h << 16);
}

// Per-axis separable weights over the 3-wide window, pre-scaled by 1/count
// (0 if count==0) and pre-shifted so base is clamped to [0, F-3].
// Shift identity (verified R7): h_k = w_{k-dB}, dB = B0 - B0clamped.
struct AxisW { float w0, w1, w2; int base; };

__device__ __forceinline__ AxisW axis_weights(float rs, float re, int p, int F) {
#pragma clang fp contract(off)
    float d  = re - rs;
    float sp = (d > 0.1f) ? d : 0.1f;
    float bs = sp / 7.0f;
    float ss = bs / 4.0f;
    float st = floorf(rs + (float)p * bs);
    int   B0 = (int)floorf(st);

    float w0 = 0.f, w1 = 0.f, w2 = 0.f; int cnt = 0;
#pragma unroll
    for (int s = 0; s < SP; ++s) {
        float v = st + ((float)s + 0.5f) * ss;
        if (v > -1.0f && v < (float)F) {
            ++cnt;
            float f1 = floorf(v);
            float dv = v - f1;
            int   i1 = (int)f1;
            int   i2 = (int)ceilf(v);
            float a  = (1.0f - dv) * ((i1 >= 0 && i1 < F) ? 1.0f : 0.0f);
            float b  = dv          * ((i2 >= 0 && i2 < F) ? 1.0f : 0.0f);
            int o1 = i1 - B0;
            int o2 = i2 - B0;
            w0 += (o1 == 0) ? a : 0.0f;
            w1 += (o1 == 1) ? a : 0.0f;
            w1 += (o2 == 1) ? b : 0.0f;
            w2 += (o2 == 2) ? b : 0.0f;
        }
    }
    float rc = (cnt > 0) ? 1.0f / (float)cnt : 0.0f;
    w0 *= rc; w1 *= rc; w2 *= rc;

    int Bc = min(max(B0, 0), F - 3);
    int dB = B0 - Bc;
    int m0 = 0 - dB, m1 = 1 - dB, m2 = 2 - dB;
    AxisW out;
    out.w0 = (m0 == 0) ? w0 : (m0 == 1) ? w1 : (m0 == 2) ? w2 : 0.0f;
    out.w1 = (m1 == 0) ? w0 : (m1 == 1) ? w1 : (m1 == 2) ? w2 : 0.0f;
    out.w2 = (m2 == 0) ? w0 : (m2 == 1) ? w1 : (m2 == 2) ? w2 : 0.0f;
    out.base = Bc;
    return out;
}

// ---- main: block = (bin, 1024-roi chunk); split slab in LDS; 3x3 window.
// 490 blocks <= 512 co-resident slots (2 blocks/CU x 16 waves = 32 waves/CU,
// LDS 46.2KB x2 fits 160KB). launch_bounds(1024,8) targets <=64 VGPR.
__global__ __launch_bounds__(RPB, 8) void roi_kernel(const float* __restrict__ ft,
                                                     const float* __restrict__ rois,
                                                     unsigned short* __restrict__ ws2,
                                                     int N, int blocksPerBin) {
    __shared__ float4 ldsA[PLANE * 2];         // channels 0-7: [pix*2+q], 36992 B
    __shared__ float2 ldsB[PLANE];             // channels 8-9: [pix],      9248 B

    const int bin   = blockIdx.x / blocksPerBin;
    const int chunk = blockIdx.x % blocksPerBin;
    const int tid   = threadIdx.x;
    const int ph    = bin / PW;
    const int pw    = bin % PW;

    // stage: consecutive-float4-per-lane LDS writes (conflict-free b128)
    {
        const float* base = ft + (size_t)bin * PLANE;
        for (int idx = tid; idx < 2 * PLANE; idx += RPB) {
            int yx = idx >> 1;
            int q  = idx & 1;
            const float* b0 = base + (size_t)(q * 4) * NP + yx;
            float4 v;
            v.x = b0[0];
            v.y = b0[NP];
            v.z = b0[2 * NP];
            v.w = b0[3 * NP];
            ldsA[idx] = v;
        }
        const float* b8 = base + (size_t)8 * NP;
        for (int yx = tid; yx < PLANE; yx += RPB) {
            float2 v;
            v.x = b8[yx];
            v.y = b8[NP + yx];
            ldsB[yx] = v;
        }
    }

    // per-roi coordinate math: independent of LDS, overlaps staging latency
    const int n = chunk * RPB + tid;
    const int nv = (n < N) ? n : 0;            // clamp for safe load; masked later
    const float* r = rois + nv * 5;
    float rx1 = r[1] * 0.125f;
    float ry1 = r[2] * 0.125f;
    float rx2 = r[3] * 0.125f;
    float ry2 = r[4] * 0.125f;
    AxisW H = axis_weights(ry1, ry2, ph, FH);
    AxisW W = axis_weights(rx1, rx2, pw, FW);
    const int base = H.base * FW + W.base;
    float rw[3] = {H.w0, H.w1, H.w2};
    float cw[3] = {W.w0, W.w1, W.w2};

    __syncthreads();

    if (n >= N) return;

    float4 a0 = make_float4(0.f,0.f,0.f,0.f);
    float4 a1 = make_float4(0.f,0.f,0.f,0.f);
    float  a8 = 0.f, a9 = 0.f;
#pragma unroll
    for (int j = 0; j < 3; ++j) {
        float wy = rw[j];
#pragma unroll
        for (int i = 0; i < 3; ++i) {
            float w = wy * cw[i];
            int pix = base + j * FW + i;
            float4 f0 = ldsA[pix * 2];
            float4 f1 = ldsA[pix * 2 + 1];
            float2 f2 = ldsB[pix];
            a0.x += w * f0.x; a0.y += w * f0.y; a0.z += w * f0.z; a0.w += w * f0.w;
            a1.x += w * f1.x; a1.y += w * f1.y; a1.z += w * f1.z; a1.w += w * f1.w;
            a8   += w * f2.x; a9   += w * f2.y;
        }
    }

    // ws2[(bin*C + c) * N + n] bf16 : lane-stride 2B, fully coalesced
    unsigned short* o = ws2 + (size_t)(bin * C) * N + n;
    o[0 * (size_t)N] = f2bf_rne(a0.x);
    o[1 * (size_t)N] = f2bf_rne(a0.y);
    o[2 * (size_t)N] = f2bf_rne(a0.z);
    o[3 * (size_t)N] = f2bf_rne(a0.w);
    o[4 * (size_t)N] = f2bf_rne(a1.x);
    o[5 * (size_t)N] = f2bf_rne(a1.y);
    o[6 * (size_t)N] = f2bf_rne(a1.z);
    o[7 * (size_t)N] = f2bf_rne(a1.w);
    o[8 * (size_t)N] = f2bf_rne(a8);
    o[9 * (size_t)N] = f2bf_rne(a9);
}

// ---- ws2 bf16 (490 x N, row r = bin*10+c) -> out fp32 (N x 490, col = c*49+bin)
__global__ __launch_bounds__(256) void transpose_out(const unsigned short* __restrict__ ws2,
                                                     float* __restrict__ out, int N) {
    __shared__ float t[NOUTC * PADW];          // 33320 B
    int n0  = blockIdx.x * TJ;
    int tid = threadIdx.x;
    bool fast = (n0 + TJ <= N) && ((N & 7) == 0);

    if (fast) {
        // one uint4 = 8 bf16 rois; 2 loads per row
        for (int idx = tid; idx < NOUTC * 2; idx += 256) {
            int r = idx >> 1;
            int half = idx & 1;
            const uint4* src = (const uint4*)(ws2 + (size_t)r * N + n0 + half * 8);
            uint4 v = *src;
            float* dst = &t[r * PADW + half * 8];
            dst[0] = bf2f((unsigned short)(v.x & 0xFFFF));
            dst[1] = bf2f((unsigned short)(v.x >> 16));
            dst[2] = bf2f((unsigned short)(v.y & 0xFFFF));
            dst[3] = bf2f((unsigned short)(v.y >> 16));
            dst[4] = bf2f((unsigned short)(v.z & 0xFFFF));
            dst[5] = bf2f((unsigned short)(v.z >> 16));
            dst[6] = bf2f((unsigned short)(v.w & 0xFFFF));
            dst[7] = bf2f((unsigned short)(v.w >> 16));
        }
    } else {
        for (int idx = tid; idx < NOUTC * TJ; idx += 256) {
            int r = idx / TJ;
            int j = idx - r * TJ;
            int n = n0 + j;
            t[r * PADW + j] = (n < N) ? bf2f(ws2[(size_t)r * N + n]) : 0.0f;
        }
    }
    __syncthreads();

    if (fast) {
        float2* out2 = (float2*)out;
        for (int idx = tid; idx < TJ * (NOUTC / 2); idx += 256) {
            int j  = idx / (NOUTC / 2);
            int t2 = idx - j * (NOUTC / 2);
            int col0 = 2 * t2, col1 = col0 + 1;
            int c0 = col0 / NBIN, b0 = col0 - c0 * NBIN;
            int c1 = col1 / NBIN, b1 = col1 - c1 * NBIN;
            float2 v;
            v.x = t[(b0 * C + c0) * PADW + j];
            v.y = t[(b1 * C + c1) * PADW + j];
            out2[(size_t)(n0 + j) * (NOUTC / 2) + t2] = v;
        }
    } else {
        for (int idx = tid; idx < TJ * NOUTC; idx += 256) {
            int j   = idx / NOUTC;
            int col = idx - j * NOUTC;
            int c   = col / NBIN;
            int b   = col - c * NBIN;
            int n   = n0 + j;
            if (n < N) out[(size_t)n * NOUTC + col] = t[(b * C + c) * PADW + j];
        }
    }
}

// ---- fallback (ws too small): inline math, direct strided store --------
__global__ __launch_bounds__(256) void roi_direct(const float* __restrict__ ft,
                                                  const float* __restrict__ rois,
                                                  float* __restrict__ out, int N) {
#pragma clang fp contract(off)
    int tid = blockIdx.x * blockDim.x + threadIdx.x;
    if (tid >= N * NBIN) return;
    int bin = tid % NBIN;
    int n   = tid / NBIN;
    int ph  = bin / PW;
    int pw  = bin % PW;
    const float* r = rois + n * 5;
    float rsw = r[1]*0.125f, rsh = r[2]*0.125f, rew = r[3]*0.125f, reh = r[4]*0.125f;
    AxisW H = axis_weights(rsh, reh, ph, FH);
    AxisW W = axis_weights(rsw, rew, pw, FW);
    float rw[3] = {H.w0, H.w1, H.w2};
    float cw[3] = {W.w0, W.w1, W.w2};
    float acc[C];
    for (int c = 0; c < C; ++c) acc[c] = 0.0f;
    const float* base = ft + (size_t)bin * PLANE;
    for (int j = 0; j < 3; ++j) {
        int y = H.base + j;
        for (int i = 0; i < 3; ++i) {
            int x = W.base + i;
            float w = rw[j] * cw[i];
            int off = y * FW + x;
            for (int c = 0; c < C; ++c)
                acc[c] += w * base[(size_t)c * NP + off];
        }
    }
    float* o = out + (size_t)n * NOUTC + bin;
    for (int c = 0; c < C; ++c) o[c * NBIN] = acc[c];
}

extern "C" void kernel_launch(void* const* d_in, const int* in_sizes, int n_in,
                              void* d_out, int out_size, void* d_ws, size_t ws_size,
                              hipStream_t stream) {
    const float* ft   = (const float*)d_in[0];
    const float* rois = (const float*)d_in[1];
    float* out = (float*)d_out;
    int N = in_sizes[1] / 5;

    size_t need = (size_t)NOUTC * N * sizeof(unsigned short);

    if (ws_size >= need) {
        unsigned short* ws2 = (unsigned short*)d_ws;
        int blocksPerBin = (N + RPB - 1) / RPB;
        roi_kernel<<<NBIN * blocksPerBin, RPB, 0, stream>>>(ft, rois, ws2,
                                                            N, blocksPerBin);
        int tblocks = (N + TJ - 1) / TJ;
        transpose_out<<<tblocks, 256, 0, stream>>>(ws2, out, N);
    } else {
        int total = N * NBIN;
        roi_direct<<<(total + 255) / 256, 256, 0, stream>>>(ft, rois, out, N);
    }
}